// Round 3
// baseline (817.055 us; speedup 1.0000x reference)
//
#include <hip/hip_runtime.h>

// ---------------------------------------------------------------------------
// Problem constants
// ---------------------------------------------------------------------------
#define B_N 16384
#define T_N 64
#define H_N 64
// output layout (floats): X_out [B,T], T10 [B], M0 [B], out [B,T,H], X_gru [B,T]
#define XOUT_OFF 0
#define T10_OFF  (B_N * T_N)
#define M0_OFF   (T10_OFF + B_N)
#define OUT_OFF  (M0_OFF + B_N)
#define XGRU_OFF (OUT_OFF + B_N * T_N * H_N)

// ws layout (bytes)
#define WS_HIDT 0
#define WS_HIDM (WS_HIDT + B_N * 64 * 4)
#define WS_W1T_HI (WS_HIDM + B_N * 64 * 4)
#define WS_W1T_LO (WS_W1T_HI + 304 * 64 * 2)
#define WS_W1M_HI (WS_W1T_LO + 304 * 64 * 2)
#define WS_W1M_LO (WS_W1M_HI + 304 * 64 * 2)
#define WS_W2T_HI (WS_W1M_LO + 304 * 64 * 2)
#define WS_W2T_LO (WS_W2T_HI + 304 * 320 * 2)
#define WS_W2M_HI (WS_W2T_LO + 304 * 320 * 2)
#define WS_W2M_LO (WS_W2M_HI + 304 * 320 * 2)

typedef float  f32x4  __attribute__((ext_vector_type(4)));
typedef __bf16 bf16x8 __attribute__((ext_vector_type(8)));
typedef __bf16 bf16x4 __attribute__((ext_vector_type(4)));

__device__ __forceinline__ f32x4 mfma16(bf16x8 a, bf16x8 b, f32x4 c) {
  return __builtin_amdgcn_mfma_f32_16x16x32_bf16(a, b, c, 0, 0, 0);
}
__device__ __forceinline__ void split8v(const float* v, bf16x8& hi, bf16x8& lo) {
#pragma unroll
  for (int i = 0; i < 8; ++i) {
    __bf16 h = (__bf16)v[i];
    hi[i] = h;
    lo[i] = (__bf16)(v[i] - (float)h);
  }
}
__device__ __forceinline__ void split4v(const float* v, bf16x4& hi, bf16x4& lo) {
#pragma unroll
  for (int i = 0; i < 4; ++i) {
    __bf16 h = (__bf16)v[i];
    hi[i] = h;
    lo[i] = (__bf16)(v[i] - (float)h);
  }
}
__device__ __forceinline__ float sigm(float x) {
  return __builtin_amdgcn_rcpf(1.f + __expf(-x));
}
__device__ __forceinline__ float tanh_f(float x) {
  return 1.f - 2.f * __builtin_amdgcn_rcpf(__expf(2.f * x) + 1.f);
}
// Raw barrier: waits LDS ops only (lgkmcnt), does NOT drain vmcnt — global
// stores float free across the scan. sched_barrier(0) pins code motion
// (rule #18 discipline for inline-asm waitcnt).
__device__ __forceinline__ void wave_barrier() {
  asm volatile("s_waitcnt lgkmcnt(0)" ::: "memory");
  __builtin_amdgcn_s_barrier();
  __builtin_amdgcn_sched_barrier(0);
}

// ---------------------------------------------------------------------------
// K1: GRU-D scan + online attention pooling. Cooperative 4-wave blocks.
// Block = 4 waves = ONE group of 16 batch rows; wave w owns j in [16w, 16w+16).
// Grid 1024 -> 4 blocks/CU (16 waves/CU).
// Raw s_barrier (no vmcnt drain); out/X_gru written as FULL 256B rows from
// LDS-staged f32 (no partial-line RMW fetch).
// LDS map (bytes):
//   0      Whc_lo [128][64]bf16, row 128B, swizzle byte^=(row&7)<<4
//   16384  hd_hi [16][64]bf16 swz; 18432 hd_lo
//   20480  rh_hi ; 22528 rh_lo
//   24576  scbuf [16][4] float2 (512B)
//   25088  ostage [16][68] f32 (4352B)
//   29440  xstage [16][68] f32 (4352B)   total 33792
// ---------------------------------------------------------------------------
#define OS_WHCLO 0
#define OS_HDH 16384
#define OS_HDL 18432
#define OS_RHH 20480
#define OS_RHL 22528
#define OS_SC  24576
#define OS_OST 25088
#define OS_XST 29440

__global__ __launch_bounds__(256, 4) void k_gru(
    const float* __restrict__ Xfa, const float* __restrict__ Xlast,
    const float* __restrict__ Xmean, const float* __restrict__ Xmask,
    const float* __restrict__ Xdelta,
    const float* __restrict__ Wgx, const float* __restrict__ bgx,
    const float* __restrict__ Wgh, const float* __restrict__ bgh,
    const float* __restrict__ Wxc, const float* __restrict__ bxc,
    const float* __restrict__ Whn, const float* __restrict__ Whc,
    const float* __restrict__ Wmc,
    const float* __restrict__ WsT, const float* __restrict__ WsM,
    float* __restrict__ dout, float* __restrict__ hidT, float* __restrict__ hidM) {
  __shared__ __align__(16) unsigned char smem[33792];
  const int tid = threadIdx.x;
  const int wv = tid >> 6, l = tid & 63, b16 = l & 15, g4 = l >> 4;
  const int brow = blockIdx.x * 16 + b16;

  // ---- cooperative Whc_lo staging into LDS (swizzled) ----
  for (int c = tid; c < 1024; c += 256) {
    const int row = c >> 3, kc = c & 7;
    const float* src = Whc + row * 64 + kc * 8;
    float v[8];
    *(float4*)&v[0] = *(const float4*)src;
    *(float4*)&v[4] = *(const float4*)(src + 4);
    bf16x8 hi, lo;
    split8v(v, hi, lo);
    *(bf16x8*)(smem + OS_WHCLO + row * 128 + ((kc * 16) ^ ((row & 7) << 4))) = lo;
  }

  // ---- per-wave W_hi fragments (+ Whn lo) in registers ----
  const int zrow = wv * 16 + b16;        // Whc z-rows [0,64)
  const int rrow = 64 + wv * 16 + b16;   // Whc r-rows [64,128)
  const int nrow = wv * 16 + b16;        // Whn rows [0,64)
  bf16x8 wz_hi[2], wr_hi[2], wn_hi[2], wn_lo[2];
#pragma unroll
  for (int kt = 0; kt < 2; ++kt) {
    float v[8];
    bf16x8 hi, lo;
    const float* s1 = Whc + zrow * 64 + kt * 32 + g4 * 8;
    *(float4*)&v[0] = *(const float4*)s1; *(float4*)&v[4] = *(const float4*)(s1 + 4);
    split8v(v, hi, lo); wz_hi[kt] = hi;
    const float* s2 = Whc + rrow * 64 + kt * 32 + g4 * 8;
    *(float4*)&v[0] = *(const float4*)s2; *(float4*)&v[4] = *(const float4*)(s2 + 4);
    split8v(v, hi, lo); wr_hi[kt] = hi;
    const float* s3 = Whn + nrow * 64 + kt * 32 + g4 * 8;
    *(float4*)&v[0] = *(const float4*)s3; *(float4*)&v[4] = *(const float4*)(s3 + 4);
    split8v(v, hi, lo); wn_hi[kt] = hi; wn_lo[kt] = lo;
  }
  // ---- ext-K A fragments (nonzero only on g4==0 lanes) ----
  bf16x8 ez = {}, er = {}, en = {};
  if (g4 == 0) {
    const int jz = zrow, jr = rrow, jn = 128 + nrow;
    float Wv, Mv, bv;
    __bf16 wh, mh, bh;
#define MKEXT(dst, WIDX, MIDX, BIDX)                                   \
    Wv = Wxc[WIDX]; Mv = Wmc[MIDX]; bv = bxc[BIDX];                    \
    wh = (__bf16)Wv; mh = (__bf16)Mv; bh = (__bf16)bv;                 \
    dst[0] = wh; dst[1] = (__bf16)(Wv - (float)wh); dst[2] = wh;       \
    dst[3] = mh; dst[4] = (__bf16)(Mv - (float)mh);                    \
    dst[5] = bh; dst[6] = (__bf16)(bv - (float)bh); dst[7] = (__bf16)0.f;
    MKEXT(ez, jz, jz, jz)
    MKEXT(er, jr, jr, jr)
    MKEXT(en, jn, jn, jn)
#undef MKEXT
  }
  // ---- per-lane scalar constants for own j = wv*16 + g4*4 + i ----
  float wgh4[4], bgh4[4], wsT4[4], wsM4[4];
#pragma unroll
  for (int i = 0; i < 4; ++i) {
    const int j = wv * 16 + g4 * 4 + i;
    wgh4[i] = Wgh[j]; bgh4[i] = bgh[j];
    wsT4[i] = WsT[j]; wsM4[i] = WsM[j];
  }
  const float wgx0 = Wgx[0], bgx0 = bgx[0];

  __syncthreads();  // one full barrier: Whc_lo staging visible

  float hcur[4] = {}, aT[4] = {}, aM[4] = {};
  float lT = 0.f, lM = 0.f;

  const int ib = brow * T_N;
  float p_xi = Xfa[ib], p_mm = Xmask[ib], p_dd = Xdelta[ib], p_xl = Xlast[ib], p_xm = Xmean[ib];
  const int swz = (b16 & 7) << 4;
  float* outp = dout + OUT_OFF;
  const int orow = wv * 4 + (l >> 4);     // full-line writer: own out row
  const int ocol = (l & 15) * 4;          // float index within row
  const long obase = (long)(blockIdx.x * 16 + orow) * 64;

  for (int t = 0; t < T_N; ++t) {
    const float xi = p_xi, mm = p_mm, dd = p_dd, xl = p_xl, xm = p_xm;
    const int tn = (t + 1 < T_N) ? t + 1 : T_N - 1;
    p_xi = Xfa[ib + tn]; p_mm = Xmask[ib + tn]; p_dd = Xdelta[ib + tn];
    p_xl = Xlast[ib + tn]; p_xm = Xmean[ib + tn];

    // decay own h slice, stage hi/lo to LDS
    float hd[4];
    {
      float v[4];
#pragma unroll
      for (int i = 0; i < 4; ++i) {
        const float gh = __expf(-fmaxf(0.f, dd * wgh4[i] + bgh4[i]));
        hd[i] = hcur[i] * gh;
        v[i] = hd[i];
      }
      bf16x4 hi4, lo4;
      split4v(v, hi4, lo4);
      const int off = (wv * 32 + g4 * 8) ^ swz;
      *(bf16x4*)(smem + OS_HDH + b16 * 128 + off) = hi4;
      *(bf16x4*)(smem + OS_HDL + b16 * 128 + off) = lo4;
    }
    // X + ext-B fragment + xstage
    const float gx = __expf(-fmaxf(0.f, dd * wgx0 + bgx0));
    const float X = mm * xi + (1.f - mm) * gx * xl + (1.f - mm) * (1.f - gx) * xm;
    if (wv == 0 && g4 == 0) *(float*)(smem + OS_XST + b16 * 272 + t * 4) = X;
    bf16x8 bext = {};
    if (g4 == 0) {
      const __bf16 xh = (__bf16)X;
      bext[0] = xh; bext[1] = xh; bext[2] = (__bf16)(X - (float)xh);
      const __bf16 mb = (__bf16)mm;
      bext[3] = mb; bext[4] = mb;
      bext[5] = (__bf16)1.f; bext[6] = (__bf16)1.f; bext[7] = (__bf16)0.f;
    }
    wave_barrier();  // B1: hd + prev {scbuf, ostage} visible

    // out write for step t-1: full 256B rows from ostage
    if (t > 0) {
      const f32x4 hv = *(const f32x4*)(smem + OS_OST + orow * 272 + ocol * 4);
      *(f32x4*)(outp + (obase + (t - 1)) * 64 + ocol) = hv;
    }
    // finalize attention for step t-1
    if (t > 0) {
      const f32x4 a = *(const f32x4*)(smem + OS_SC + b16 * 32);
      const f32x4 c = *(const f32x4*)(smem + OS_SC + b16 * 32 + 16);
      const float pT = __expf(a[0] + a[2] + c[0] + c[2]);
      const float pM = __expf(a[1] + a[3] + c[1] + c[3]);
      lT += pT; lM += pM;
#pragma unroll
      for (int i = 0; i < 4; ++i) { aT[i] += pT * hcur[i]; aM[i] += pM * hcur[i]; }
    }

    // G1: z,r pre-activations — split into 2 independent MFMA chains each
    f32x4 za = {0.f, 0.f, 0.f, 0.f}, zb = za, ra = za, rb = za;
    bf16x8 bh[2], bl[2];
#pragma unroll
    for (int kt = 0; kt < 2; ++kt) {
      const int boff = (kt * 64 + g4 * 16) ^ swz;
      bh[kt] = *(const bf16x8*)(smem + OS_HDH + b16 * 128 + boff);
      bl[kt] = *(const bf16x8*)(smem + OS_HDL + b16 * 128 + boff);
    }
#pragma unroll
    for (int kt = 0; kt < 2; ++kt) {
      const int aoff = kt * 64 + g4 * 16;
      const bf16x8 zlo = *(const bf16x8*)(smem + OS_WHCLO + zrow * 128 + (aoff ^ ((zrow & 7) << 4)));
      const bf16x8 rlo = *(const bf16x8*)(smem + OS_WHCLO + rrow * 128 + (aoff ^ ((rrow & 7) << 4)));
      za = mfma16(wz_hi[kt], bh[kt], za);
      zb = mfma16(zlo, bh[kt], zb);
      ra = mfma16(wr_hi[kt], bh[kt], ra);
      rb = mfma16(rlo, bh[kt], rb);
    }
#pragma unroll
    for (int kt = 0; kt < 2; ++kt) {
      zb = mfma16(wz_hi[kt], bl[kt], zb);
      rb = mfma16(wr_hi[kt], bl[kt], rb);
    }
    za = mfma16(ez, bext, za);
    ra = mfma16(er, bext, ra);

    float zz[4], rh[4];
#pragma unroll
    for (int i = 0; i < 4; ++i) {
      zz[i] = sigm(za[i] + zb[i]);
      rh[i] = sigm(ra[i] + rb[i]) * hd[i];
    }
    {
      bf16x4 hi4, lo4;
      split4v(rh, hi4, lo4);
      const int off = (wv * 32 + g4 * 8) ^ swz;
      *(bf16x4*)(smem + OS_RHH + b16 * 128 + off) = hi4;
      *(bf16x4*)(smem + OS_RHL + b16 * 128 + off) = lo4;
    }
    wave_barrier();  // B2: rh visible

    // G2: (r*h) @ W_hn^T (+ ext fold), split chains
    f32x4 na = {0.f, 0.f, 0.f, 0.f}, nb = na;
#pragma unroll
    for (int kt = 0; kt < 2; ++kt) {
      const int boff = (kt * 64 + g4 * 16) ^ swz;
      const bf16x8 ch = *(const bf16x8*)(smem + OS_RHH + b16 * 128 + boff);
      const bf16x8 cl = *(const bf16x8*)(smem + OS_RHL + b16 * 128 + boff);
      na = mfma16(wn_hi[kt], ch, na);
      nb = mfma16(wn_lo[kt], ch, nb);
      nb = mfma16(wn_hi[kt], cl, nb);
    }
    na = mfma16(en, bext, na);

    // h update + stage h_new (f32) + new scores
    float scT = 0.f, scM = 0.f;
    f32x4 ho;
#pragma unroll
    for (int i = 0; i < 4; ++i) {
      const float ht = tanh_f(na[i] + nb[i]);
      const float hn = (1.f - zz[i]) * hd[i] + zz[i] * ht;
      hcur[i] = hn;
      ho[i] = hn;
      scT += hn * wsT4[i];
      scM += hn * wsM4[i];
    }
    *(f32x4*)(smem + OS_OST + b16 * 272 + (wv * 16 + g4 * 4) * 4) = ho;
    scT += __shfl_xor(scT, 16); scT += __shfl_xor(scT, 32);
    scM += __shfl_xor(scM, 16); scM += __shfl_xor(scM, 32);
    if (l < 16) {
      float2 sc = {scT, scM};
      *(float2*)(smem + OS_SC + b16 * 32 + wv * 8) = sc;
    }
  }
  wave_barrier();  // final drain: t=63 scbuf/ostage + xstage visible

  // out row t=63 + X_gru full rows
  {
    const f32x4 hv = *(const f32x4*)(smem + OS_OST + orow * 272 + ocol * 4);
    *(f32x4*)(outp + (obase + 63) * 64 + ocol) = hv;
    const f32x4 xv = *(const f32x4*)(smem + OS_XST + orow * 272 + ocol * 4);
    *(f32x4*)(dout + XGRU_OFF + obase + ocol) = xv;
  }
  // finalize last step's attention
  {
    const f32x4 a = *(const f32x4*)(smem + OS_SC + b16 * 32);
    const f32x4 c = *(const f32x4*)(smem + OS_SC + b16 * 32 + 16);
    const float pT = __expf(a[0] + a[2] + c[0] + c[2]);
    const float pM = __expf(a[1] + a[3] + c[1] + c[3]);
    lT += pT; lM += pM;
#pragma unroll
    for (int i = 0; i < 4; ++i) { aT[i] += pT * hcur[i]; aM[i] += pM * hcur[i]; }
  }
  const float invT = 1.f / lT, invM = 1.f / lM;
  f32x4 vT, vM;
#pragma unroll
  for (int i = 0; i < 4; ++i) { vT[i] = aT[i] * invT; vM[i] = aM[i] * invM; }
  *(f32x4*)(hidT + brow * 64 + wv * 16 + g4 * 4) = vT;
  *(f32x4*)(hidM + brow * 64 + wv * 16 + g4 * 4) = vM;
}

// ---------------------------------------------------------------------------
// K0: split MLP weights into bf16 hi/lo with zero padding (W1:[304][64], W2:[304][320])
// ---------------------------------------------------------------------------
__device__ __forceinline__ void wsplit(float v, unsigned short* hi, unsigned short* lo, int idx) {
  union { __bf16 b; unsigned short u; } c;
  __bf16 hb = (__bf16)v;
  c.b = hb; hi[idx] = c.u;
  c.b = (__bf16)(v - (float)hb); lo[idx] = c.u;
}
__global__ void k_prep(const float* __restrict__ Wt1, const float* __restrict__ Wm1,
                       const float* __restrict__ Wt2, const float* __restrict__ Wm2,
                       unsigned short* w1t_hi, unsigned short* w1t_lo,
                       unsigned short* w1m_hi, unsigned short* w1m_lo,
                       unsigned short* w2t_hi, unsigned short* w2t_lo,
                       unsigned short* w2m_hi, unsigned short* w2m_lo) {
  const int i = blockIdx.x * 256 + threadIdx.x;  // grid covers exactly 304*320
  if (i < 304 * 64) {
    const int r = i >> 6, c = i & 63;
    const float vt = (r < 300) ? Wt1[r * 64 + c] : 0.f;
    const float vm = (r < 300) ? Wm1[r * 64 + c] : 0.f;
    wsplit(vt, w1t_hi, w1t_lo, i);
    wsplit(vm, w1m_hi, w1m_lo, i);
  }
  {
    const int r = i / 320, c = i - r * 320;
    const bool ok = (r < 300) && (c < 300);
    const float vt = ok ? Wt2[r * 300 + c] : 0.f;
    const float vm = ok ? Wm2[r * 300 + c] : 0.f;
    wsplit(vt, w2t_hi, w2t_lo, i);
    wsplit(vm, w2m_hi, w2m_lo, i);
  }
}

// ---------------------------------------------------------------------------
// K2: MLP head. 512 blocks: [0,256) T-path, [256,512) M-path. 64 rows/block.
// ---------------------------------------------------------------------------
__global__ __launch_bounds__(256, 2) void k_mlp(
    const float* __restrict__ hidT, const float* __restrict__ hidM,
    const unsigned short* __restrict__ w1t_hi, const unsigned short* __restrict__ w1t_lo,
    const unsigned short* __restrict__ w1m_hi, const unsigned short* __restrict__ w1m_lo,
    const unsigned short* __restrict__ w2t_hi, const unsigned short* __restrict__ w2t_lo,
    const unsigned short* __restrict__ w2m_hi, const unsigned short* __restrict__ w2m_lo,
    const float* __restrict__ bt1, const float* __restrict__ bt2,
    const float* __restrict__ Wt3, const float* __restrict__ bt3,
    const float* __restrict__ bm1, const float* __restrict__ bm2,
    const float* __restrict__ Wm3, const float* __restrict__ bm3,
    float* __restrict__ dout) {
  __shared__ __align__(16) unsigned char smem[44608];
  const int tid = threadIdx.x;
  const int blk = blockIdx.x & 255;
  const bool isM = blockIdx.x >= 256;
  const float* hid = isM ? hidM : hidT;
  const unsigned short* w1hi = isM ? w1m_hi : w1t_hi;
  const unsigned short* w1lo = isM ? w1m_lo : w1t_lo;
  const unsigned short* w2hi = isM ? w2m_hi : w2t_hi;
  const unsigned short* w2lo = isM ? w2m_lo : w2t_lo;
  const float* b1 = isM ? bm1 : bt1;
  const float* b2 = isM ? bm2 : bt2;
  const float* w3 = isM ? Wm3 : Wt3;
  const float b3 = (isM ? bm3 : bt3)[0];
  const float LOV = isM ? 0.1f : 0.2f;
  const float HIV = isM ? 20.f : 5.0f;
  float* headp = dout + (isM ? M0_OFF : T10_OFF);

  float* sb1 = (float*)(smem + 40960);
  float* sb2 = (float*)(smem + 42176);
  float* sw3 = (float*)(smem + 43392);
  for (int i = tid; i < 304; i += 256) {
    sb1[i] = (i < 300) ? b1[i] : 0.f;
    sb2[i] = (i < 300) ? b2[i] : 0.f;
    sw3[i] = (i < 300) ? w3[i] : 0.f;
  }
  __syncthreads();

  const int wv = tid >> 6, l = tid & 63, b16 = l & 15, g4 = l >> 4;
  const int b = blk * 64 + wv * 16 + b16;
  const int h1off = wv * 10240;

  // L1: hid -> 304 (3-term compensated)
  bf16x8 b1h[2], b1l[2];
#pragma unroll
  for (int kt = 0; kt < 2; ++kt) {
    const float* hp = hid + b * 64 + kt * 32 + g4 * 8;
    float v[8];
    *(float4*)&v[0] = *(const float4*)hp;
    *(float4*)&v[4] = *(const float4*)(hp + 4);
    split8v(v, b1h[kt], b1l[kt]);
  }
  f32x4 acc1[19];
#pragma unroll
  for (int jt = 0; jt < 19; ++jt) {
    f32x4 acc = {0.f, 0.f, 0.f, 0.f};
#pragma unroll
    for (int kt = 0; kt < 2; ++kt) {
      const int row = jt * 16 + b16;
      bf16x8 ahi = *(const bf16x8*)(w1hi + row * 64 + kt * 32 + g4 * 8);
      bf16x8 alo = *(const bf16x8*)(w1lo + row * 64 + kt * 32 + g4 * 8);
      acc = mfma16(ahi, b1h[kt], acc);
      acc = mfma16(alo, b1h[kt], acc);
      acc = mfma16(ahi, b1l[kt], acc);
    }
    acc1[jt] = acc;
  }
  // zero k-pad cols [304,320) of own rows (pre-swizzle offsets [608,640))
  if (g4 == 0) {
#pragma unroll
    for (int q = 0; q < 4; ++q) {
      const int off = (608 + q * 8) ^ ((b16 & 7) << 4);
      *(unsigned long long*)(smem + h1off + b16 * 640 + off) = 0ull;
    }
  }
  // bias + ELU -> stage h1 (bf16) in swizzled LDS
#pragma unroll
  for (int jt = 0; jt < 19; ++jt) {
    bf16x4 hv;
#pragma unroll
    for (int i = 0; i < 4; ++i) {
      const int j = jt * 16 + g4 * 4 + i;
      const float v = acc1[jt][i] + sb1[j];
      const float e = (v > 0.f) ? v : (__expf(v) - 1.f);
      hv[i] = (__bf16)e;
    }
    const int off = (jt * 32 + g4 * 8) ^ ((b16 & 7) << 4);
    *(bf16x4*)(smem + h1off + b16 * 640 + off) = hv;
  }
  // L2 (2-term) with fused L3 dot
  bf16x8 bh2[10];
#pragma unroll
  for (int kt = 0; kt < 10; ++kt) {
    const int off = (kt * 64 + g4 * 16) ^ ((b16 & 7) << 4);
    bh2[kt] = *(const bf16x8*)(smem + h1off + b16 * 640 + off);
  }
  float raw = 0.f;
#pragma unroll
  for (int jt = 0; jt < 19; ++jt) {
    f32x4 acc = {0.f, 0.f, 0.f, 0.f};
#pragma unroll
    for (int kt = 0; kt < 10; ++kt) {
      const int row = jt * 16 + b16;
      bf16x8 ahi = *(const bf16x8*)(w2hi + row * 320 + kt * 32 + g4 * 8);
      bf16x8 alo = *(const bf16x8*)(w2lo + row * 320 + kt * 32 + g4 * 8);
      acc = mfma16(ahi, bh2[kt], acc);
      acc = mfma16(alo, bh2[kt], acc);
    }
#pragma unroll
    for (int i = 0; i < 4; ++i) {
      const int j = jt * 16 + g4 * 4 + i;
      const float v = acc[i] + sb2[j];
      const float e = (v > 0.f) ? v : (__expf(v) - 1.f);
      raw += e * sw3[j];
    }
  }
  raw += __shfl_xor(raw, 16);
  raw += __shfl_xor(raw, 32);
  if (l < 16) {
    const float rr = raw + b3;
    headp[b] = LOV + (HIV - LOV) / (1.f + __expf(-rr));
  }
}

// ---------------------------------------------------------------------------
// K3: X_out epilogue
// ---------------------------------------------------------------------------
__global__ void k_final(const float* __restrict__ fav, const float* __restrict__ TR,
                        float* __restrict__ dout) {
  const int i = blockIdx.x * 256 + threadIdx.x;  // < B*T
  const int bb = i >> 6;
  const float T10v = dout[T10_OFF + bb];
  const float M0v = dout[M0_OFF + bb];
  const float e = __expf(-TR[bb] / T10v);
  const float fa = fav[i];
  float s, c;
  __sincosf(fa, &s, &c);
  dout[i] = (1.f - e) * s / (1.f - c * e) * M0v;
}

// ---------------------------------------------------------------------------
extern "C" void kernel_launch(void* const* d_in, const int* in_sizes, int n_in,
                              void* d_out, int out_size, void* d_ws, size_t ws_size,
                              hipStream_t stream) {
  const float* Xfa   = (const float*)d_in[0];
  const float* Xlast = (const float*)d_in[1];
  const float* Xmean = (const float*)d_in[2];
  const float* Xmask = (const float*)d_in[3];
  const float* Xdelta= (const float*)d_in[4];
  const float* fav   = (const float*)d_in[5];
  const float* TR    = (const float*)d_in[6];
  const float* Wgx   = (const float*)d_in[7];
  const float* bgx   = (const float*)d_in[8];
  const float* Wgh   = (const float*)d_in[9];
  const float* bgh   = (const float*)d_in[10];
  const float* Wxc   = (const float*)d_in[11];
  const float* bxc   = (const float*)d_in[12];
  const float* Whn   = (const float*)d_in[13];
  const float* Whc   = (const float*)d_in[14];
  const float* Wmc   = (const float*)d_in[15];
  const float* WsT   = (const float*)d_in[16];
  const float* WsM   = (const float*)d_in[17];
  const float* Wt1   = (const float*)d_in[18];
  const float* bt1   = (const float*)d_in[19];
  const float* Wt2   = (const float*)d_in[20];
  const float* bt2   = (const float*)d_in[21];
  const float* Wt3   = (const float*)d_in[22];
  const float* bt3   = (const float*)d_in[23];
  const float* Wm1   = (const float*)d_in[24];
  const float* bm1   = (const float*)d_in[25];
  const float* Wm2   = (const float*)d_in[26];
  const float* bm2   = (const float*)d_in[27];
  const float* Wm3   = (const float*)d_in[28];
  const float* bm3   = (const float*)d_in[29];

  float* dout = (float*)d_out;
  char* ws = (char*)d_ws;
  float* hidT = (float*)(ws + WS_HIDT);
  float* hidM = (float*)(ws + WS_HIDM);
  unsigned short* w1t_hi = (unsigned short*)(ws + WS_W1T_HI);
  unsigned short* w1t_lo = (unsigned short*)(ws + WS_W1T_LO);
  unsigned short* w1m_hi = (unsigned short*)(ws + WS_W1M_HI);
  unsigned short* w1m_lo = (unsigned short*)(ws + WS_W1M_LO);
  unsigned short* w2t_hi = (unsigned short*)(ws + WS_W2T_HI);
  unsigned short* w2t_lo = (unsigned short*)(ws + WS_W2T_LO);
  unsigned short* w2m_hi = (unsigned short*)(ws + WS_W2M_HI);
  unsigned short* w2m_lo = (unsigned short*)(ws + WS_W2M_LO);

  k_prep<<<380, 256, 0, stream>>>(Wt1, Wm1, Wt2, Wm2, w1t_hi, w1t_lo, w1m_hi, w1m_lo,
                                  w2t_hi, w2t_lo, w2m_hi, w2m_lo);
  k_gru<<<1024, 256, 0, stream>>>(Xfa, Xlast, Xmean, Xmask, Xdelta, Wgx, bgx, Wgh, bgh, Wxc, bxc,
                                  Whn, Whc, Wmc, WsT, WsM, dout, hidT, hidM);
  k_mlp<<<512, 256, 0, stream>>>(hidT, hidM, w1t_hi, w1t_lo, w1m_hi, w1m_lo, w2t_hi, w2t_lo,
                                 w2m_hi, w2m_lo, bt1, bt2, Wt3, bt3, bm1, bm2, Wm3, bm3, dout);
  k_final<<<4096, 256, 0, stream>>>(fav, TR, dout);
}

// Round 4
// 580.404 us; speedup vs baseline: 1.4077x; 1.4077x over previous
//
#include <hip/hip_runtime.h>

// ---------------------------------------------------------------------------
// Problem constants
// ---------------------------------------------------------------------------
#define B_N 16384
#define T_N 64
#define H_N 64
// output layout (floats): X_out [B,T], T10 [B], M0 [B], out [B,T,H], X_gru [B,T]
#define XOUT_OFF 0
#define T10_OFF  (B_N * T_N)
#define M0_OFF   (T10_OFF + B_N)
#define OUT_OFF  (M0_OFF + B_N)
#define XGRU_OFF (OUT_OFF + B_N * T_N * H_N)

// ws layout (bytes)
#define WS_HIDT 0
#define WS_HIDM (WS_HIDT + B_N * 64 * 4)
#define WS_W1T_HI (WS_HIDM + B_N * 64 * 4)
#define WS_W1T_LO (WS_W1T_HI + 304 * 64 * 2)
#define WS_W1M_HI (WS_W1T_LO + 304 * 64 * 2)
#define WS_W1M_LO (WS_W1M_HI + 304 * 64 * 2)
#define WS_W2T_HI (WS_W1M_LO + 304 * 64 * 2)
#define WS_W2T_LO (WS_W2T_HI + 304 * 320 * 2)
#define WS_W2M_HI (WS_W2T_LO + 304 * 320 * 2)
#define WS_W2M_LO (WS_W2M_HI + 304 * 320 * 2)

typedef float  f32x4  __attribute__((ext_vector_type(4)));
typedef __bf16 bf16x8 __attribute__((ext_vector_type(8)));
typedef __bf16 bf16x4 __attribute__((ext_vector_type(4)));

__device__ __forceinline__ f32x4 mfma16(bf16x8 a, bf16x8 b, f32x4 c) {
  return __builtin_amdgcn_mfma_f32_16x16x32_bf16(a, b, c, 0, 0, 0);
}
__device__ __forceinline__ void split8v(const float* v, bf16x8& hi, bf16x8& lo) {
#pragma unroll
  for (int i = 0; i < 8; ++i) {
    __bf16 h = (__bf16)v[i];
    hi[i] = h;
    lo[i] = (__bf16)(v[i] - (float)h);
  }
}
__device__ __forceinline__ void split4v(const float* v, bf16x4& hi, bf16x4& lo) {
#pragma unroll
  for (int i = 0; i < 4; ++i) {
    __bf16 h = (__bf16)v[i];
    hi[i] = h;
    lo[i] = (__bf16)(v[i] - (float)h);
  }
}
__device__ __forceinline__ float sigm(float x) {
  return __builtin_amdgcn_rcpf(1.f + __expf(-x));
}
__device__ __forceinline__ float tanh_f(float x) {
  return 1.f - 2.f * __builtin_amdgcn_rcpf(__expf(2.f * x) + 1.f);
}
// Raw barrier: waits LDS ops only (lgkmcnt), does NOT drain vmcnt. Safe here
// because the t-loop contains ZERO global loads and its stores are never read
// back. sched_barrier(0) pins code motion (rule #18 discipline).
__device__ __forceinline__ void wave_barrier() {
  asm volatile("s_waitcnt lgkmcnt(0)" ::: "memory");
  __builtin_amdgcn_s_barrier();
  __builtin_amdgcn_sched_barrier(0);
}

// ---------------------------------------------------------------------------
// K1: GRU-D scan + online attention pooling. Cooperative 4-wave blocks.
// Block = 4 waves = ONE group of 16 batch rows; wave w owns j in [16w, 16w+16).
// Grid 1024 -> 4 blocks/CU (16 waves/CU).
// ALL inputs pre-staged in LDS; t-loop's only vmem = streaming out-store (NT).
// LDS map (bytes):
//   0      instage [5][64][16] f32 (20480)  layout [arr][t][row]: conflict-free
//   20480  hd_hi [16][64]bf16 swz(row&7)<<4 ; 22528 hd_lo
//   24576  rh_hi ; 26624 rh_lo
//   28672  scbuf [16][4] float2 (512)
//   29184  ostage [16][68] f32 (4352)
//   33536  xstage [16][68] f32 (4352)    total 37888 (4 blocks/CU: 4x <= 160K)
// ---------------------------------------------------------------------------
#define OS_IN  0
#define OS_HDH 20480
#define OS_HDL 22528
#define OS_RHH 24576
#define OS_RHL 26624
#define OS_SC  28672
#define OS_OST 29184
#define OS_XST 33536

__global__ __launch_bounds__(256, 4) void k_gru(
    const float* __restrict__ Xfa, const float* __restrict__ Xlast,
    const float* __restrict__ Xmean, const float* __restrict__ Xmask,
    const float* __restrict__ Xdelta,
    const float* __restrict__ Wgx, const float* __restrict__ bgx,
    const float* __restrict__ Wgh, const float* __restrict__ bgh,
    const float* __restrict__ Wxc, const float* __restrict__ bxc,
    const float* __restrict__ Whn, const float* __restrict__ Whc,
    const float* __restrict__ Wmc,
    const float* __restrict__ WsT, const float* __restrict__ WsM,
    float* __restrict__ dout, float* __restrict__ hidT, float* __restrict__ hidM) {
  __shared__ __align__(16) unsigned char smem[37888];
  const int tid = threadIdx.x;
  const int wv = tid >> 6, l = tid & 63, b16 = l & 15, g4 = l >> 4;
  const int brow = blockIdx.x * 16 + b16;

  // ---- stage ALL inputs for this block's 16 rows into LDS ----
  // thread tid handles (r = tid>>4, tq = tid&15): one float4 per array.
  {
    const int r = tid >> 4, tq = tid & 15;
    const long gsrc = (long)(blockIdx.x * 16 + r) * 64 + tq * 4;
#pragma unroll
    for (int a = 0; a < 5; ++a) {
      const float* src = (a == 0) ? Xfa : (a == 1) ? Xmask : (a == 2) ? Xdelta
                         : (a == 3) ? Xlast : Xmean;
      const float4 v = *(const float4*)(src + gsrc);
      float* dst = (float*)(smem + OS_IN + a * 4096);
#pragma unroll
      for (int j = 0; j < 4; ++j) dst[(tq * 4 + j) * 16 + r] = ((const float*)&v)[j];
    }
  }

  // ---- per-wave W fragments (hi AND lo) in registers ----
  const int zrow = wv * 16 + b16;        // Whc z-rows [0,64)
  const int rrow = 64 + wv * 16 + b16;   // Whc r-rows [64,128)
  const int nrow = wv * 16 + b16;        // Whn rows [0,64)
  bf16x8 wz_hi[2], wz_lo[2], wr_hi[2], wr_lo[2], wn_hi[2], wn_lo[2];
#pragma unroll
  for (int kt = 0; kt < 2; ++kt) {
    float v[8];
    const float* s1 = Whc + zrow * 64 + kt * 32 + g4 * 8;
    *(float4*)&v[0] = *(const float4*)s1; *(float4*)&v[4] = *(const float4*)(s1 + 4);
    split8v(v, wz_hi[kt], wz_lo[kt]);
    const float* s2 = Whc + rrow * 64 + kt * 32 + g4 * 8;
    *(float4*)&v[0] = *(const float4*)s2; *(float4*)&v[4] = *(const float4*)(s2 + 4);
    split8v(v, wr_hi[kt], wr_lo[kt]);
    const float* s3 = Whn + nrow * 64 + kt * 32 + g4 * 8;
    *(float4*)&v[0] = *(const float4*)s3; *(float4*)&v[4] = *(const float4*)(s3 + 4);
    split8v(v, wn_hi[kt], wn_lo[kt]);
  }
  // ---- ext-K A fragments (nonzero only on g4==0 lanes) ----
  bf16x8 ez = {}, er = {}, en = {};
  if (g4 == 0) {
    const int jz = zrow, jr = rrow, jn = 128 + nrow;
    float Wv, Mv, bv;
    __bf16 wh, mh, bh;
#define MKEXT(dst, WIDX, MIDX, BIDX)                                   \
    Wv = Wxc[WIDX]; Mv = Wmc[MIDX]; bv = bxc[BIDX];                    \
    wh = (__bf16)Wv; mh = (__bf16)Mv; bh = (__bf16)bv;                 \
    dst[0] = wh; dst[1] = (__bf16)(Wv - (float)wh); dst[2] = wh;       \
    dst[3] = mh; dst[4] = (__bf16)(Mv - (float)mh);                    \
    dst[5] = bh; dst[6] = (__bf16)(bv - (float)bh); dst[7] = (__bf16)0.f;
    MKEXT(ez, jz, jz, jz)
    MKEXT(er, jr, jr, jr)
    MKEXT(en, jn, jn, jn)
#undef MKEXT
  }
  // ---- per-lane scalar constants for own j = wv*16 + g4*4 + i ----
  float wgh4[4], bgh4[4], wsT4[4], wsM4[4];
#pragma unroll
  for (int i = 0; i < 4; ++i) {
    const int j = wv * 16 + g4 * 4 + i;
    wgh4[i] = Wgh[j]; bgh4[i] = bgh[j];
    wsT4[i] = WsT[j]; wsM4[i] = WsM[j];
  }
  const float wgx0 = Wgx[0], bgx0 = bgx[0];

  __syncthreads();  // full barrier once: input staging visible (drains all)

  float hcur[4] = {}, aT[4] = {}, aM[4] = {};
  float lT = 0.f, lM = 0.f;

  const int swz = (b16 & 7) << 4;
  float* outp = dout + OUT_OFF;
  const int orow = wv * 4 + g4;           // full-line writer: own out row
  const int ocol = b16 * 4;               // float index within row
  const long obase = (long)(blockIdx.x * 16 + orow) * 64;
  const float* instage = (const float*)(smem + OS_IN);

  for (int t = 0; t < T_N; ++t) {
    // inputs from LDS (broadcast-friendly: 16 addrs stride 4B, 4-way bcast)
    const float xi = instage[0 * 1024 + t * 16 + b16];
    const float mm = instage[1 * 1024 + t * 16 + b16];
    const float dd = instage[2 * 1024 + t * 16 + b16];
    const float xl = instage[3 * 1024 + t * 16 + b16];
    const float xm = instage[4 * 1024 + t * 16 + b16];

    // decay own h slice, stage hi/lo to LDS
    float hd[4];
    {
      float v[4];
#pragma unroll
      for (int i = 0; i < 4; ++i) {
        const float gh = __expf(-fmaxf(0.f, dd * wgh4[i] + bgh4[i]));
        hd[i] = hcur[i] * gh;
        v[i] = hd[i];
      }
      bf16x4 hi4, lo4;
      split4v(v, hi4, lo4);
      const int off = (wv * 32 + g4 * 8) ^ swz;
      *(bf16x4*)(smem + OS_HDH + b16 * 128 + off) = hi4;
      *(bf16x4*)(smem + OS_HDL + b16 * 128 + off) = lo4;
    }
    // X + ext-B fragment + xstage
    const float gx = __expf(-fmaxf(0.f, dd * wgx0 + bgx0));
    const float X = mm * xi + (1.f - mm) * gx * xl + (1.f - mm) * (1.f - gx) * xm;
    if (wv == 0 && g4 == 0) *(float*)(smem + OS_XST + b16 * 272 + t * 4) = X;
    bf16x8 bext = {};
    if (g4 == 0) {
      const __bf16 xh = (__bf16)X;
      bext[0] = xh; bext[1] = xh; bext[2] = (__bf16)(X - (float)xh);
      const __bf16 mb = (__bf16)mm;
      bext[3] = mb; bext[4] = mb;
      bext[5] = (__bf16)1.f; bext[6] = (__bf16)1.f; bext[7] = (__bf16)0.f;
    }
    wave_barrier();  // B1: hd + prev {scbuf, ostage} visible

    // out write for step t-1: full 256B rows from ostage (non-temporal)
    if (t > 0) {
      const f32x4 hv = *(const f32x4*)(smem + OS_OST + orow * 272 + ocol * 4);
      __builtin_nontemporal_store(hv, (f32x4*)(outp + (obase + (t - 1)) * 64 + ocol));
    }
    // finalize attention for step t-1
    if (t > 0) {
      const f32x4 a = *(const f32x4*)(smem + OS_SC + b16 * 32);
      const f32x4 c = *(const f32x4*)(smem + OS_SC + b16 * 32 + 16);
      const float pT = __expf(a[0] + a[2] + c[0] + c[2]);
      const float pM = __expf(a[1] + a[3] + c[1] + c[3]);
      lT += pT; lM += pM;
#pragma unroll
      for (int i = 0; i < 4; ++i) { aT[i] += pT * hcur[i]; aM[i] += pM * hcur[i]; }
    }

    // G1: z,r pre-activations — 2 independent MFMA chains each (3-term comp.)
    f32x4 za = {0.f, 0.f, 0.f, 0.f}, zb = za, ra = za, rb = za;
    bf16x8 bh[2], bl[2];
#pragma unroll
    for (int kt = 0; kt < 2; ++kt) {
      const int boff = (kt * 64 + g4 * 16) ^ swz;
      bh[kt] = *(const bf16x8*)(smem + OS_HDH + b16 * 128 + boff);
      bl[kt] = *(const bf16x8*)(smem + OS_HDL + b16 * 128 + boff);
    }
#pragma unroll
    for (int kt = 0; kt < 2; ++kt) {
      za = mfma16(wz_hi[kt], bh[kt], za);
      zb = mfma16(wz_lo[kt], bh[kt], zb);
      ra = mfma16(wr_hi[kt], bh[kt], ra);
      rb = mfma16(wr_lo[kt], bh[kt], rb);
    }
#pragma unroll
    for (int kt = 0; kt < 2; ++kt) {
      zb = mfma16(wz_hi[kt], bl[kt], zb);
      rb = mfma16(wr_hi[kt], bl[kt], rb);
    }
    za = mfma16(ez, bext, za);
    ra = mfma16(er, bext, ra);

    float zz[4], rh[4];
#pragma unroll
    for (int i = 0; i < 4; ++i) {
      zz[i] = sigm(za[i] + zb[i]);
      rh[i] = sigm(ra[i] + rb[i]) * hd[i];
    }
    {
      bf16x4 hi4, lo4;
      split4v(rh, hi4, lo4);
      const int off = (wv * 32 + g4 * 8) ^ swz;
      *(bf16x4*)(smem + OS_RHH + b16 * 128 + off) = hi4;
      *(bf16x4*)(smem + OS_RHL + b16 * 128 + off) = lo4;
    }
    wave_barrier();  // B2: rh visible

    // G2: (r*h) @ W_hn^T (+ ext fold), split chains
    f32x4 na = {0.f, 0.f, 0.f, 0.f}, nb = na;
#pragma unroll
    for (int kt = 0; kt < 2; ++kt) {
      const int boff = (kt * 64 + g4 * 16) ^ swz;
      const bf16x8 ch = *(const bf16x8*)(smem + OS_RHH + b16 * 128 + boff);
      const bf16x8 cl = *(const bf16x8*)(smem + OS_RHL + b16 * 128 + boff);
      na = mfma16(wn_hi[kt], ch, na);
      nb = mfma16(wn_lo[kt], ch, nb);
      nb = mfma16(wn_hi[kt], cl, nb);
    }
    na = mfma16(en, bext, na);

    // h update + stage h_new (f32) + new scores
    float scT = 0.f, scM = 0.f;
    f32x4 ho;
#pragma unroll
    for (int i = 0; i < 4; ++i) {
      const float ht = tanh_f(na[i] + nb[i]);
      const float hn = (1.f - zz[i]) * hd[i] + zz[i] * ht;
      hcur[i] = hn;
      ho[i] = hn;
      scT += hn * wsT4[i];
      scM += hn * wsM4[i];
    }
    *(f32x4*)(smem + OS_OST + b16 * 272 + (wv * 16 + g4 * 4) * 4) = ho;
    scT += __shfl_xor(scT, 16); scT += __shfl_xor(scT, 32);
    scM += __shfl_xor(scM, 16); scM += __shfl_xor(scM, 32);
    if (l < 16) {
      float2 sc = {scT, scM};
      *(float2*)(smem + OS_SC + b16 * 32 + wv * 8) = sc;
    }
  }
  wave_barrier();  // final drain: t=63 scbuf/ostage + xstage visible

  // out row t=63 + X_gru full rows
  {
    const f32x4 hv = *(const f32x4*)(smem + OS_OST + orow * 272 + ocol * 4);
    __builtin_nontemporal_store(hv, (f32x4*)(outp + (obase + 63) * 64 + ocol));
    const f32x4 xv = *(const f32x4*)(smem + OS_XST + orow * 272 + ocol * 4);
    *(f32x4*)(dout + XGRU_OFF + obase + ocol) = xv;
  }
  // finalize last step's attention
  {
    const f32x4 a = *(const f32x4*)(smem + OS_SC + b16 * 32);
    const f32x4 c = *(const f32x4*)(smem + OS_SC + b16 * 32 + 16);
    const float pT = __expf(a[0] + a[2] + c[0] + c[2]);
    const float pM = __expf(a[1] + a[3] + c[1] + c[3]);
    lT += pT; lM += pM;
#pragma unroll
    for (int i = 0; i < 4; ++i) { aT[i] += pT * hcur[i]; aM[i] += pM * hcur[i]; }
  }
  const float invT = 1.f / lT, invM = 1.f / lM;
  f32x4 vT, vM;
#pragma unroll
  for (int i = 0; i < 4; ++i) { vT[i] = aT[i] * invT; vM[i] = aM[i] * invM; }
  *(f32x4*)(hidT + brow * 64 + wv * 16 + g4 * 4) = vT;
  *(f32x4*)(hidM + brow * 64 + wv * 16 + g4 * 4) = vM;
}

// ---------------------------------------------------------------------------
// K0: split MLP weights into bf16 hi/lo with zero padding (W1:[304][64], W2:[304][320])
// ---------------------------------------------------------------------------
__device__ __forceinline__ void wsplit(float v, unsigned short* hi, unsigned short* lo, int idx) {
  union { __bf16 b; unsigned short u; } c;
  __bf16 hb = (__bf16)v;
  c.b = hb; hi[idx] = c.u;
  c.b = (__bf16)(v - (float)hb); lo[idx] = c.u;
}
__global__ void k_prep(const float* __restrict__ Wt1, const float* __restrict__ Wm1,
                       const float* __restrict__ Wt2, const float* __restrict__ Wm2,
                       unsigned short* w1t_hi, unsigned short* w1t_lo,
                       unsigned short* w1m_hi, unsigned short* w1m_lo,
                       unsigned short* w2t_hi, unsigned short* w2t_lo,
                       unsigned short* w2m_hi, unsigned short* w2m_lo) {
  const int i = blockIdx.x * 256 + threadIdx.x;  // grid covers exactly 304*320
  if (i < 304 * 64) {
    const int r = i >> 6, c = i & 63;
    const float vt = (r < 300) ? Wt1[r * 64 + c] : 0.f;
    const float vm = (r < 300) ? Wm1[r * 64 + c] : 0.f;
    wsplit(vt, w1t_hi, w1t_lo, i);
    wsplit(vm, w1m_hi, w1m_lo, i);
  }
  {
    const int r = i / 320, c = i - r * 320;
    const bool ok = (r < 300) && (c < 300);
    const float vt = ok ? Wt2[r * 300 + c] : 0.f;
    const float vm = ok ? Wm2[r * 300 + c] : 0.f;
    wsplit(vt, w2t_hi, w2t_lo, i);
    wsplit(vm, w2m_hi, w2m_lo, i);
  }
}

// ---------------------------------------------------------------------------
// K2: MLP head. 512 blocks: [0,256) T-path, [256,512) M-path. 64 rows/block.
// ---------------------------------------------------------------------------
__global__ __launch_bounds__(256, 2) void k_mlp(
    const float* __restrict__ hidT, const float* __restrict__ hidM,
    const unsigned short* __restrict__ w1t_hi, const unsigned short* __restrict__ w1t_lo,
    const unsigned short* __restrict__ w1m_hi, const unsigned short* __restrict__ w1m_lo,
    const unsigned short* __restrict__ w2t_hi, const unsigned short* __restrict__ w2t_lo,
    const unsigned short* __restrict__ w2m_hi, const unsigned short* __restrict__ w2m_lo,
    const float* __restrict__ bt1, const float* __restrict__ bt2,
    const float* __restrict__ Wt3, const float* __restrict__ bt3,
    const float* __restrict__ bm1, const float* __restrict__ bm2,
    const float* __restrict__ Wm3, const float* __restrict__ bm3,
    float* __restrict__ dout) {
  __shared__ __align__(16) unsigned char smem[44608];
  const int tid = threadIdx.x;
  const int blk = blockIdx.x & 255;
  const bool isM = blockIdx.x >= 256;
  const float* hid = isM ? hidM : hidT;
  const unsigned short* w1hi = isM ? w1m_hi : w1t_hi;
  const unsigned short* w1lo = isM ? w1m_lo : w1t_lo;
  const unsigned short* w2hi = isM ? w2m_hi : w2t_hi;
  const unsigned short* w2lo = isM ? w2m_lo : w2t_lo;
  const float* b1 = isM ? bm1 : bt1;
  const float* b2 = isM ? bm2 : bt2;
  const float* w3 = isM ? Wm3 : Wt3;
  const float b3 = (isM ? bm3 : bt3)[0];
  const float LOV = isM ? 0.1f : 0.2f;
  const float HIV = isM ? 20.f : 5.0f;
  float* headp = dout + (isM ? M0_OFF : T10_OFF);

  float* sb1 = (float*)(smem + 40960);
  float* sb2 = (float*)(smem + 42176);
  float* sw3 = (float*)(smem + 43392);
  for (int i = tid; i < 304; i += 256) {
    sb1[i] = (i < 300) ? b1[i] : 0.f;
    sb2[i] = (i < 300) ? b2[i] : 0.f;
    sw3[i] = (i < 300) ? w3[i] : 0.f;
  }
  __syncthreads();

  const int wv = tid >> 6, l = tid & 63, b16 = l & 15, g4 = l >> 4;
  const int b = blk * 64 + wv * 16 + b16;
  const int h1off = wv * 10240;

  // L1: hid -> 304 (3-term compensated)
  bf16x8 b1h[2], b1l[2];
#pragma unroll
  for (int kt = 0; kt < 2; ++kt) {
    const float* hp = hid + b * 64 + kt * 32 + g4 * 8;
    float v[8];
    *(float4*)&v[0] = *(const float4*)hp;
    *(float4*)&v[4] = *(const float4*)(hp + 4);
    split8v(v, b1h[kt], b1l[kt]);
  }
  f32x4 acc1[19];
#pragma unroll
  for (int jt = 0; jt < 19; ++jt) {
    f32x4 acc = {0.f, 0.f, 0.f, 0.f};
#pragma unroll
    for (int kt = 0; kt < 2; ++kt) {
      const int row = jt * 16 + b16;
      bf16x8 ahi = *(const bf16x8*)(w1hi + row * 64 + kt * 32 + g4 * 8);
      bf16x8 alo = *(const bf16x8*)(w1lo + row * 64 + kt * 32 + g4 * 8);
      acc = mfma16(ahi, b1h[kt], acc);
      acc = mfma16(alo, b1h[kt], acc);
      acc = mfma16(ahi, b1l[kt], acc);
    }
    acc1[jt] = acc;
  }
  // zero k-pad cols [304,320) of own rows (pre-swizzle offsets [608,640))
  if (g4 == 0) {
#pragma unroll
    for (int q = 0; q < 4; ++q) {
      const int off = (608 + q * 8) ^ ((b16 & 7) << 4);
      *(unsigned long long*)(smem + h1off + b16 * 640 + off) = 0ull;
    }
  }
  // bias + ELU -> stage h1 (bf16) in swizzled LDS
#pragma unroll
  for (int jt = 0; jt < 19; ++jt) {
    bf16x4 hv;
#pragma unroll
    for (int i = 0; i < 4; ++i) {
      const int j = jt * 16 + g4 * 4 + i;
      const float v = acc1[jt][i] + sb1[j];
      const float e = (v > 0.f) ? v : (__expf(v) - 1.f);
      hv[i] = (__bf16)e;
    }
    const int off = (jt * 32 + g4 * 8) ^ ((b16 & 7) << 4);
    *(bf16x4*)(smem + h1off + b16 * 640 + off) = hv;
  }
  // L2 (2-term) with fused L3 dot
  bf16x8 bh2[10];
#pragma unroll
  for (int kt = 0; kt < 10; ++kt) {
    const int off = (kt * 64 + g4 * 16) ^ ((b16 & 7) << 4);
    bh2[kt] = *(const bf16x8*)(smem + h1off + b16 * 640 + off);
  }
  float raw = 0.f;
#pragma unroll
  for (int jt = 0; jt < 19; ++jt) {
    f32x4 acc = {0.f, 0.f, 0.f, 0.f};
#pragma unroll
    for (int kt = 0; kt < 10; ++kt) {
      const int row = jt * 16 + b16;
      bf16x8 ahi = *(const bf16x8*)(w2hi + row * 320 + kt * 32 + g4 * 8);
      bf16x8 alo = *(const bf16x8*)(w2lo + row * 320 + kt * 32 + g4 * 8);
      acc = mfma16(ahi, bh2[kt], acc);
      acc = mfma16(alo, bh2[kt], acc);
    }
#pragma unroll
    for (int i = 0; i < 4; ++i) {
      const int j = jt * 16 + g4 * 4 + i;
      const float v = acc[i] + sb2[j];
      const float e = (v > 0.f) ? v : (__expf(v) - 1.f);
      raw += e * sw3[j];
    }
  }
  raw += __shfl_xor(raw, 16);
  raw += __shfl_xor(raw, 32);
  if (l < 16) {
    const float rr = raw + b3;
    headp[b] = LOV + (HIV - LOV) / (1.f + __expf(-rr));
  }
}

// ---------------------------------------------------------------------------
// K3: X_out epilogue
// ---------------------------------------------------------------------------
__global__ void k_final(const float* __restrict__ fav, const float* __restrict__ TR,
                        float* __restrict__ dout) {
  const int i = blockIdx.x * 256 + threadIdx.x;  // < B*T
  const int bb = i >> 6;
  const float T10v = dout[T10_OFF + bb];
  const float M0v = dout[M0_OFF + bb];
  const float e = __expf(-TR[bb] / T10v);
  const float fa = fav[i];
  float s, c;
  __sincosf(fa, &s, &c);
  dout[i] = (1.f - e) * s / (1.f - c * e) * M0v;
}

// ---------------------------------------------------------------------------
extern "C" void kernel_launch(void* const* d_in, const int* in_sizes, int n_in,
                              void* d_out, int out_size, void* d_ws, size_t ws_size,
                              hipStream_t stream) {
  const float* Xfa   = (const float*)d_in[0];
  const float* Xlast = (const float*)d_in[1];
  const float* Xmean = (const float*)d_in[2];
  const float* Xmask = (const float*)d_in[3];
  const float* Xdelta= (const float*)d_in[4];
  const float* fav   = (const float*)d_in[5];
  const float* TR    = (const float*)d_in[6];
  const float* Wgx   = (const float*)d_in[7];
  const float* bgx   = (const float*)d_in[8];
  const float* Wgh   = (const float*)d_in[9];
  const float* bgh   = (const float*)d_in[10];
  const float* Wxc   = (const float*)d_in[11];
  const float* bxc   = (const float*)d_in[12];
  const float* Whn   = (const float*)d_in[13];
  const float* Whc   = (const float*)d_in[14];
  const float* Wmc   = (const float*)d_in[15];
  const float* WsT   = (const float*)d_in[16];
  const float* WsM   = (const float*)d_in[17];
  const float* Wt1   = (const float*)d_in[18];
  const float* bt1   = (const float*)d_in[19];
  const float* Wt2   = (const float*)d_in[20];
  const float* bt2   = (const float*)d_in[21];
  const float* Wt3   = (const float*)d_in[22];
  const float* bt3   = (const float*)d_in[23];
  const float* Wm1   = (const float*)d_in[24];
  const float* bm1   = (const float*)d_in[25];
  const float* Wm2   = (const float*)d_in[26];
  const float* bm2   = (const float*)d_in[27];
  const float* Wm3   = (const float*)d_in[28];
  const float* bm3   = (const float*)d_in[29];

  float* dout = (float*)d_out;
  char* ws = (char*)d_ws;
  float* hidT = (float*)(ws + WS_HIDT);
  float* hidM = (float*)(ws + WS_HIDM);
  unsigned short* w1t_hi = (unsigned short*)(ws + WS_W1T_HI);
  unsigned short* w1t_lo = (unsigned short*)(ws + WS_W1T_LO);
  unsigned short* w1m_hi = (unsigned short*)(ws + WS_W1M_HI);
  unsigned short* w1m_lo = (unsigned short*)(ws + WS_W1M_LO);
  unsigned short* w2t_hi = (unsigned short*)(ws + WS_W2T_HI);
  unsigned short* w2t_lo = (unsigned short*)(ws + WS_W2T_LO);
  unsigned short* w2m_hi = (unsigned short*)(ws + WS_W2M_HI);
  unsigned short* w2m_lo = (unsigned short*)(ws + WS_W2M_LO);

  k_prep<<<380, 256, 0, stream>>>(Wt1, Wm1, Wt2, Wm2, w1t_hi, w1t_lo, w1m_hi, w1m_lo,
                                  w2t_hi, w2t_lo, w2m_hi, w2m_lo);
  k_gru<<<1024, 256, 0, stream>>>(Xfa, Xlast, Xmean, Xmask, Xdelta, Wgx, bgx, Wgh, bgh, Wxc, bxc,
                                  Whn, Whc, Wmc, WsT, WsM, dout, hidT, hidM);
  k_mlp<<<512, 256, 0, stream>>>(hidT, hidM, w1t_hi, w1t_lo, w1m_hi, w1m_lo, w2t_hi, w2t_lo,
                                 w2m_hi, w2m_lo, bt1, bt2, Wt3, bt3, bm1, bm2, Wm3, bm3, dout);
  k_final<<<4096, 256, 0, stream>>>(fav, TR, dout);
}